// Round 7
// baseline (411.573 us; speedup 1.0000x reference)
//
#include <hip/hip_runtime.h>
#include <hip/hip_bf16.h>

// Problem constants (fixed by setup_inputs)
#define B_  2
#define C_  256
#define H_  64
#define W_  128
#define N_  (H_ * W_)   // 8192
#define K_  32          // top-k
#define Q_  10          // per-lane register queue depth (32 queues/row)
#define CK2 36          // candidates per row handed to stage 2 (bf16-sorted)
#define TN  32          // n-rows per block
#define TM  16          // m-rows per wave per m-tile
#define NHT 64          // m-tiles per wave (1024 m / 16)
#define RR  16          // rank rows per block (16*36 = 576 threads exact)
#define BCAP 40960      // per-bucket pair capacity (mean 36864, +22 sigma)

typedef short  short8  __attribute__((ext_vector_type(8)));
typedef short  short4v __attribute__((ext_vector_type(4)));
typedef float  floatx4 __attribute__((ext_vector_type(4)));

__device__ __forceinline__ unsigned umin_(unsigned a, unsigned b) { return a < b ? a : b; }
__device__ __forceinline__ unsigned umax_(unsigned a, unsigned b) { return a > b ? a : b; }
__device__ __forceinline__ ushort f2bf(float v) {
    __hip_bfloat16 h = __float2bfloat16(v);   // RNE
    ushort u; __builtin_memcpy(&u, &h, 2); return u;
}
// hardware median-of-3 (valid as shift-insert because q[i] <= q[i-1])
__device__ __forceinline__ unsigned med3u(unsigned a, unsigned b, unsigned c) {
    unsigned d;
    asm("v_med3_u32 %0, %1, %2, %3" : "=v"(d) : "v"(a), "v"(b), "v"(c));
    return d;
}

// key: top-19 bits of fp32 (clamped >=0, monotone) | 13-bit m index
__device__ __forceinline__ unsigned packkey(float v, int m) {
    const float vc = v > 0.0f ? v : 0.0f;
    unsigned b; __builtin_memcpy(&b, &vc, 4);
    return (b & 0xFFFFE000u) | (unsigned)m;
}

// descending-sorted register queue insert via v_med3_u32
__device__ __forceinline__ void qinsert(unsigned (&q)[Q_], unsigned k) {
#pragma unroll
    for (int i = Q_ - 1; i > 0; --i)
        q[i] = med3u(q[i - 1], k, q[i]);
    q[0] = umax_(q[0], k);
}

#define CSWAP(a, b) { const unsigned _mx = umax_(a, b); \
                      const unsigned _mn = umin_(a, b); (a) = _mx; (b) = _mn; }

// async global->LDS DMA, 16 B per lane. LDS dest is wave-uniform base +
// lane*16 (HW-added); global src is per-lane.
__device__ __forceinline__ void gl_lds16(const ushort* g, ushort* l) {
    __builtin_amdgcn_global_load_lds(
        (const __attribute__((address_space(1))) unsigned int*)(g),
        (__attribute__((address_space(3))) unsigned int*)(l),
        16, 0, 0);
}

// ---------------------------------------------------------------------------
// Kernel 1: prep (vectorized). fp32 [B][C][N] -> f1Tf fp32 [B][N][C],
//           f2Tf fp32 [B][N][C], f2T bf16 [B][N][C]
// ---------------------------------------------------------------------------
__global__ void raft_prep_kernel(const float* __restrict__ f1,
                                 const float* __restrict__ f2,
                                 float* __restrict__ f1Tf,
                                 ushort* __restrict__ f2T,
                                 float* __restrict__ f2Tf) {
    __shared__ float tile[32][33];
    const int nt = blockIdx.x;
    const int ct = blockIdx.y;
    const int z  = blockIdx.z;          // b*2 + which
    const int b  = z >> 1;
    const float* __restrict__ src = (z & 1) ? f2 : f1;
    const int tid = threadIdx.x;

    {
        const int cl = tid >> 3;        // 0..31
        const int nx = tid & 7;         // 0..7 (x4 n)
        const float4 v = *(const float4*)(
            src + ((size_t)b * C_ + (ct * 32 + cl)) * N_ + (nt * 32 + nx * 4));
        tile[cl][nx * 4 + 0] = v.x;
        tile[cl][nx * 4 + 1] = v.y;
        tile[cl][nx * 4 + 2] = v.z;
        tile[cl][nx * 4 + 3] = v.w;
    }
    __syncthreads();
    {
        const int nl = tid >> 3;        // 0..31
        const int c4 = (tid & 7) * 4;   // 0,4,..28
        float4 v;
        v.x = tile[c4 + 0][nl];
        v.y = tile[c4 + 1][nl];
        v.z = tile[c4 + 2][nl];
        v.w = tile[c4 + 3][nl];
        const size_t o = ((size_t)b * N_ + (nt * 32 + nl)) * C_ + (ct * 32 + c4);
        if (z & 1) {
            *(float4*)(f2Tf + o) = v;
            short4v h;
            h[0] = (short)f2bf(v.x); h[1] = (short)f2bf(v.y);
            h[2] = (short)f2bf(v.z); h[3] = (short)f2bf(v.w);
            *(short4v*)(f2T + o) = h;
        } else {
            *(float4*)(f1Tf + o) = v;
        }
    }
}

// ---------------------------------------------------------------------------
// Kernel 2: stage-1 (ROUND-4 VERBATIM, measured 159 us). 512 thr = 8 waves,
// each wave owns a private m-eighth and holds BOTH n-strips in registers
// (af[2]) -> each ds_read_b128 feeds 2 MFMAs; staged bytes written once (DMA)
// + read once. K split into two 128-col phases with LDS double-buffer; one
// __syncthreads per phase (its vmcnt(0) drain is the DMA completion wait).
// ---------------------------------------------------------------------------
__launch_bounds__(512, 4)
__global__ void raft_stage1_kernel(const float* __restrict__ f1Tf,
                                   const ushort* __restrict__ f2T,
                                   ushort* __restrict__ cand) {
    // [kh][eighth][16 rows x 16 chunks x 8 ushorts] = 2 x 32 KiB
    __shared__ __align__(16) ushort Bt[2][8][2048];

    // XCD-bijective swizzle: 512 = 8 XCDs x 64; each XCD serves one batch.
    const int bid0 = blockIdx.x;
    const int bid  = ((bid0 & 7) << 6) | (bid0 >> 3);
    const int b    = bid >> 8;
    const int nt0  = (bid & 255) * TN;
    const int tid  = threadIdx.x;
    const int w    = tid >> 6;                   // wave 0..7 = m-eighth
    const int lane = tid & 63;
    const int p    = lane & 15;
    const int q4   = lane >> 4;

    // ---- f1 fragments (B-operand), both n-strips: fp32 -> bf16 RNE ----
    short8 af[2][8];
    #pragma unroll
    for (int ns = 0; ns < 2; ++ns) {
        const float* __restrict__ arow =
            f1Tf + ((size_t)b * N_ + nt0 + ns * 16 + p) * C_;
        #pragma unroll
        for (int ks = 0; ks < 8; ++ks) {
            const float4 x = *(const float4*)(arow + ks * 32 + q4 * 8);
            const float4 y = *(const float4*)(arow + ks * 32 + q4 * 8 + 4);
            short8 t;
            t[0] = (short)f2bf(x.x); t[1] = (short)f2bf(x.y);
            t[2] = (short)f2bf(x.z); t[3] = (short)f2bf(x.w);
            t[4] = (short)f2bf(y.x); t[5] = (short)f2bf(y.y);
            t[6] = (short)f2bf(y.z); t[7] = (short)f2bf(y.w);
            af[ns][ks] = t;
        }
    }

    unsigned q0[Q_], q1[Q_];
    #pragma unroll
    for (int i = 0; i < Q_; ++i) { q0[i] = 0u; q1[i] = 0u; }

    // ---- DMA source map: half-tile = 2048 slots of 16 B, slot s holds
    //      global (row r, chunk c = c' ^ (r&7)) of eighth es; linear LDS.
    //      s = w*64 + i*512 + lane  (i = 0..3 instrs per wave)
    const ushort* __restrict__ f2Tb = f2T + (size_t)b * N_ * C_;
    const ushort* gsrc[4];
    #pragma unroll
    for (int i = 0; i < 4; ++i) {
        const int s  = w * 64 + i * 512 + lane;
        const int es = s >> 8;                 // 0..7
        const int r  = (s >> 4) & 15;          // row in sub-tile
        const int cc = (s & 15) ^ (r & 7);     // source chunk (inverse swizzle)
        gsrc[i] = f2Tb + ((size_t)es * 1024 + r) * C_ + cc * 8;
    }
    const int sbase = (w * 64) * 8;            // ushort offset of wave slot base

    // ---- prologue: DMA (mt=0, kh=0) into Bt[0] ----
    #pragma unroll
    for (int i = 0; i < 4; ++i)
        gl_lds16(gsrc[i], &Bt[0][0][0] + sbase + i * 512 * 8);
    __syncthreads();

    floatx4 acc0, acc1;
    for (int mt = 0; mt < NHT; ++mt) {
        // ============ phase kh = 0 : read Bt[0], stage (mt,1) -> Bt[1] ======
        {
            const size_t off = (size_t)mt * TM * C_ + 128;
            #pragma unroll
            for (int i = 0; i < 4; ++i)
                gl_lds16(gsrc[i] + off, &Bt[1][0][0] + sbase + i * 512 * 8);
        }
        acc0 = (floatx4){0.f, 0.f, 0.f, 0.f};
        acc1 = (floatx4){0.f, 0.f, 0.f, 0.f};
        {
            const ushort* __restrict__ cur = &Bt[0][w][0];
            #pragma unroll
            for (int ks = 0; ks < 4; ++ks) {
                const int c = ks * 4 + q4;
                const short8 bm = *(const short8*)(&cur[(p * 16 + (c ^ (p & 7))) * 8]);
                acc0 = __builtin_amdgcn_mfma_f32_16x16x32_bf16(bm, af[0][ks], acc0, 0, 0, 0);
                acc1 = __builtin_amdgcn_mfma_f32_16x16x32_bf16(bm, af[1][ks], acc1, 0, 0, 0);
            }
        }
        __syncthreads();   // Bt[1] DMA landed; everyone done reading Bt[0]

        // ============ phase kh = 1 : read Bt[1], stage (mt+1,0) -> Bt[0] ====
        if (mt + 1 < NHT) {
            const size_t off = (size_t)(mt + 1) * TM * C_;
            #pragma unroll
            for (int i = 0; i < 4; ++i)
                gl_lds16(gsrc[i] + off, &Bt[0][0][0] + sbase + i * 512 * 8);
        }
        {
            const ushort* __restrict__ cur = &Bt[1][w][0];
            #pragma unroll
            for (int ks = 0; ks < 4; ++ks) {
                const int c = ks * 4 + q4;
                const short8 bm = *(const short8*)(&cur[(p * 16 + (c ^ (p & 7))) * 8]);
                acc0 = __builtin_amdgcn_mfma_f32_16x16x32_bf16(bm, af[0][4 + ks], acc0, 0, 0, 0);
                acc1 = __builtin_amdgcn_mfma_f32_16x16x32_bf16(bm, af[1][4 + ks], acc1, 0, 0, 0);
            }
        }

        // ---- in-register filter: same m-class, two n-rows ----
        const int mb = w * 1024 + mt * TM + q4 * 4;
        {
            unsigned k0 = packkey(acc0[0], mb + 0);
            unsigned k1 = packkey(acc0[1], mb + 1);
            unsigned k2 = packkey(acc0[2], mb + 2);
            unsigned k3 = packkey(acc0[3], mb + 3);
            CSWAP(k0, k1); CSWAP(k2, k3); CSWAP(k0, k2); CSWAP(k1, k3); CSWAP(k1, k2);
            qinsert(q0, k0);
            if (__any(k1 > q0[Q_ - 1])) {
                qinsert(q0, k1);
                if (__any(k2 > q0[Q_ - 1])) {
                    qinsert(q0, k2);
                    if (__any(k3 > q0[Q_ - 1])) qinsert(q0, k3);
                }
            }
        }
        {
            unsigned k0 = packkey(acc1[0], mb + 0);
            unsigned k1 = packkey(acc1[1], mb + 1);
            unsigned k2 = packkey(acc1[2], mb + 2);
            unsigned k3 = packkey(acc1[3], mb + 3);
            CSWAP(k0, k1); CSWAP(k2, k3); CSWAP(k0, k2); CSWAP(k1, k3); CSWAP(k1, k2);
            qinsert(q1, k0);
            if (__any(k1 > q1[Q_ - 1])) {
                qinsert(q1, k1);
                if (__any(k2 > q1[Q_ - 1])) {
                    qinsert(q1, k2);
                    if (__any(k3 > q1[Q_ - 1])) qinsert(q1, k3);
                }
            }
        }
        __syncthreads();   // Bt[0] DMA landed; everyone done reading Bt[1]
    }

    // ---- tail: 32 sorted depth-10 lists per row -> bf16-sorted top-36 ----
    unsigned* __restrict__ smem = (unsigned*)&Bt[0][0][0];
    const int qi = w * 4 + q4;
    #pragma unroll
    for (int t = 0; t < Q_; ++t) {
        smem[(qi * Q_ + t) * 33 + p]      = q0[t];
        smem[(qi * Q_ + t) * 33 + 16 + p] = q1[t];
    }
    __syncthreads();

    // stage A: 128 threads: (row r, group g of 8 lists) 8-way merge -> top-36
    unsigned* __restrict__ ms = smem + 10560;    // 32*10*33 span
    if (tid < 128) {
        const int r = tid >> 2, g = tid & 3;
        const int lb = g * 8;
        int i0 = 0, i1 = 0, i2 = 0, i3 = 0, i4 = 0, i5 = 0, i6 = 0, i7 = 0;
        for (int t = 0; t < CK2; ++t) {
            const unsigned a0 = (i0 < Q_) ? smem[((lb + 0) * Q_ + i0) * 33 + r] : 0u;
            const unsigned a1 = (i1 < Q_) ? smem[((lb + 1) * Q_ + i1) * 33 + r] : 0u;
            const unsigned a2 = (i2 < Q_) ? smem[((lb + 2) * Q_ + i2) * 33 + r] : 0u;
            const unsigned a3 = (i3 < Q_) ? smem[((lb + 3) * Q_ + i3) * 33 + r] : 0u;
            const unsigned a4 = (i4 < Q_) ? smem[((lb + 4) * Q_ + i4) * 33 + r] : 0u;
            const unsigned a5 = (i5 < Q_) ? smem[((lb + 5) * Q_ + i5) * 33 + r] : 0u;
            const unsigned a6 = (i6 < Q_) ? smem[((lb + 6) * Q_ + i6) * 33 + r] : 0u;
            const unsigned a7 = (i7 < Q_) ? smem[((lb + 7) * Q_ + i7) * 33 + r] : 0u;
            const unsigned mx = umax_(umax_(umax_(a0, a1), umax_(a2, a3)),
                                      umax_(umax_(a4, a5), umax_(a6, a7)));
            ms[(g * CK2 + t) * 33 + r] = mx;
            const bool e0 = (a0 == mx);
            const bool e1 = !e0 && (a1 == mx);
            const bool e2 = !e0 && !e1 && (a2 == mx);
            const bool e3 = !e0 && !e1 && !e2 && (a3 == mx);
            const bool e4 = !e0 && !e1 && !e2 && !e3 && (a4 == mx);
            const bool e5 = !e0 && !e1 && !e2 && !e3 && !e4 && (a5 == mx);
            const bool e6 = !e0 && !e1 && !e2 && !e3 && !e4 && !e5 && (a6 == mx);
            const bool e7 = !e0 && !e1 && !e2 && !e3 && !e4 && !e5 && !e6 && (a7 == mx);
            i0 += e0; i1 += e1; i2 += e2; i3 += e3;
            i4 += e4; i5 += e5; i6 += e6; i7 += e7;
        }
    }
    __syncthreads();

    // stage B: 32 threads (one per row): 4-way merge, take first 36, emit idx
    if (tid < 32) {
        int i0 = 0, i1 = 0, i2 = 0, i3 = 0;
        ushort* __restrict__ myc = cand + ((size_t)(b * N_ + nt0 + tid)) * CK2;
        for (int t = 0; t < CK2; ++t) {
            const unsigned a0 = ms[(0 * CK2 + i0) * 33 + tid];
            const unsigned a1 = ms[(1 * CK2 + i1) * 33 + tid];
            const unsigned a2 = ms[(2 * CK2 + i2) * 33 + tid];
            const unsigned a3 = ms[(3 * CK2 + i3) * 33 + tid];
            const unsigned m01 = umax_(a0, a1), m23 = umax_(a2, a3);
            const unsigned mx  = umax_(m01, m23);
            myc[t] = (ushort)(mx & 0x1FFFu);
            i0 += (a0 == mx);
            i1 += (a0 != mx) & (a1 == mx);
            i2 += (a0 != mx) & (a1 != mx) & (a2 == mx);
            i3 += (a0 != mx) & (a1 != mx) & (a2 != mx) & (a3 == mx);
        }
    }
}

// ---------------------------------------------------------------------------
// Kernel 3a: zero the 16 bucket counters (they live in the dead f2T region,
// which prep fills -- so zero after stage-1, not before).
// ---------------------------------------------------------------------------
__global__ void raft_zero_kernel(unsigned* __restrict__ gcnt) {
    if (threadIdx.x < 16) gcnt[threadIdx.x] = 0u;
}

// ---------------------------------------------------------------------------
// Kernel 3b: scatter (row,j) pairs into 16 buckets keyed by (batch, m>>10).
// Two-level: LDS histogram, one global atomicAdd reservation per bin per
// block, LDS-local cursors. Each block owns 64 consecutive rows -> pairs in
// a bucket arrive in ~64-row runs (f1-side L2 locality for the score pass).
// ---------------------------------------------------------------------------
__launch_bounds__(256)
__global__ void raft_scatter_kernel(const ushort* __restrict__ cand,
                                    unsigned* __restrict__ pairs,
                                    unsigned* __restrict__ gcnt) {
    __shared__ unsigned h[16], base[16];
    const int bid = blockIdx.x;                  // 0..255
    const int tid = threadIdx.x;                 // 0..255
    const int row = bid * 64 + (tid >> 2);       // this thread's row
    const int j0  = (tid & 3) * 9;               // 9 candidates per thread
    const int bb  = row >> 13;
    if (tid < 16) h[tid] = 0u;
    __syncthreads();
    ushort mloc[9];
    #pragma unroll
    for (int u = 0; u < 9; ++u) {
        const ushort m = cand[(size_t)row * CK2 + j0 + u];
        mloc[u] = m;
        atomicAdd(&h[bb * 8 + (m >> 10)], 1u);
    }
    __syncthreads();
    if (tid < 16) { base[tid] = atomicAdd(&gcnt[tid], h[tid]); h[tid] = 0u; }
    __syncthreads();
    #pragma unroll
    for (int u = 0; u < 9; ++u) {
        const int bkt = bb * 8 + (mloc[u] >> 10);
        const unsigned idx = base[bkt] + atomicAdd(&h[bkt], 1u);
        pairs[(size_t)bkt * BCAP + idx] = ((unsigned)row << 6) | (unsigned)(j0 + u);
    }
}

// ---------------------------------------------------------------------------
// Kernel 3c: score -- bucketed exact-fp32 re-score. Bucket = (b, m>>10);
// mt = blockIdx%8 so each XCD (round-robin heuristic) serves one m-tile:
// its 2 buckets' f2 tiles (2 MB) stay L2-resident; f1 streams in 64-row
// runs. fmaf sequence identical to the old rerank -> bit-identical scores.
// ---------------------------------------------------------------------------
__launch_bounds__(256)
__global__ void raft_score_kernel(const float* __restrict__ f1Tf,
                                  const float* __restrict__ f2Tf,
                                  const ushort* __restrict__ cand,
                                  const unsigned* __restrict__ pairs,
                                  const unsigned* __restrict__ gcnt,
                                  float* __restrict__ cs) {
    const int bid = blockIdx.x;                  // 0..1023
    const int mt  = bid & 7;
    const int bb  = (bid >> 3) & 1;
    const int sl  = bid >> 4;                    // slice 0..63
    const int bkt = bb * 8 + mt;
    const unsigned cnt = umin_(gcnt[bkt], (unsigned)BCAP);
    const unsigned lo = (cnt * (unsigned)sl) >> 6;
    const unsigned hi = (cnt * (unsigned)(sl + 1)) >> 6;
    const unsigned* __restrict__ pb = pairs + (size_t)bkt * BCAP;
    for (unsigned i = lo + threadIdx.x; i < hi; i += 256) {
        const unsigned pid = pb[i];
        const unsigned row = pid >> 6;
        const unsigned j   = pid & 63;
        const int m = cand[(size_t)row * CK2 + j];
        const float* __restrict__ aRow = f1Tf + (size_t)row * C_;
        const float* __restrict__ bRow = f2Tf + ((size_t)bb * N_ + m) * C_;
        float acc = 0.0f;
        for (int c4 = 0; c4 < C_; c4 += 4) {
            const float4 a4 = *(const float4*)(aRow + c4);
            const float4 b4 = *(const float4*)(bRow + c4);
            acc = fmaf(a4.x, b4.x, acc);
            acc = fmaf(a4.y, b4.y, acc);
            acc = fmaf(a4.z, b4.z, acc);
            acc = fmaf(a4.w, b4.w, acc);
        }
        cs[(size_t)row * CK2 + j] = acc;
    }
}

// ---------------------------------------------------------------------------
// Kernel 4: rank + epilogue (old rerank minus the dot phase).
// grid: 1024 blocks x 576 threads = 16 rows x 36 candidates.
// ---------------------------------------------------------------------------
__launch_bounds__(576)
__global__ void raft_rank_kernel(const ushort* __restrict__ cand,
                                 const float* __restrict__ cs,
                                 float* __restrict__ out) {
    __shared__ float  csS[RR][CK2];
    __shared__ ushort cmS[RR][CK2];
    const int bid0 = blockIdx.x;                        // 0..1023
    const int bid  = ((bid0 & 7) << 7) | (bid0 >> 3);   // XCD-bijective
    const int row0 = bid * RR;
    const int tid  = threadIdx.x;      // 0..575
    const int r    = tid / CK2;        // 0..15
    const int c    = tid - r * CK2;    // 0..35

    cmS[r][c] = cand[(size_t)(row0 + r) * CK2 + c];
    csS[r][c] = cs[(size_t)(row0 + r) * CK2 + c];
    __syncthreads();

    const int rg = row0 + r;
    const int bb = rg >> 13;
    const int n  = rg & (N_ - 1);
    const int y0 = n >> 7, x0 = n & 127;
    {
        const float v = csS[r][c];
        const int m = cmS[r][c];
        int rank = 0;
        for (int j = 0; j < CK2; ++j) {
            const float vj = csS[r][j];
            rank += (vj > v) || ((vj == v) && (cmS[r][j] < m));
        }
        if (rank < K_) {
            const size_t posn = (size_t)rank * N_ + n;
            out[(size_t)bb * (K_ * N_) + posn] = v * 0.0625f;   // /sqrt(256), exact
            const size_t c1b = (size_t)1572864 + (size_t)bb * 2 * K_ * N_;
            out[c1b + posn]                     = (float)((m >> 7) - y0);
            out[c1b + (size_t)(K_ * N_) + posn] = (float)((m & 127) - x0);
        }
    }
    if (c < K_) {
        const size_t posn = (size_t)c * N_ + n;
        const size_t c0b = (size_t)524288 + (size_t)bb * 2 * K_ * N_;
        out[c0b + posn]                     = (float)y0;
        out[c0b + (size_t)(K_ * N_) + posn] = (float)x0;
        out[(size_t)2621440 + (size_t)bb * (K_ * N_) + posn] = (float)bb;
    }
}

// ---------------------------------------------------------------------------
extern "C" void kernel_launch(void* const* d_in, const int* in_sizes, int n_in,
                              void* d_out, int out_size, void* d_ws, size_t ws_size,
                              hipStream_t stream) {
    const float* f1 = (const float*)d_in[0];   // [B][C][N] fp32
    const float* f2 = (const float*)d_in[1];

    float*  f1Tf = (float*)d_ws;                             // 16,777,216 B
    float*  f2Tf = f1Tf + (size_t)B_ * N_ * C_;              // 16,777,216 B
    ushort* f2T  = (ushort*)(f2Tf + (size_t)B_ * N_ * C_);   //  8,388,608 B
    ushort* cand = f2T + (size_t)B_ * N_ * C_;               //  1,179,648 B

    // f2T region is dead after stage-1; overlay the rerank scratch there:
    unsigned* pairs = (unsigned*)f2T;                        // 2,621,440 B
    float*    cs    = (float*)((char*)f2T + 2621440);        // 2,359,296 B
    unsigned* gcnt  = (unsigned*)((char*)f2T + 4980736);     //        64 B

    raft_prep_kernel<<<dim3(N_ / 32, C_ / 32, B_ * 2), dim3(256), 0, stream>>>(
        f1, f2, f1Tf, f2T, f2Tf);

    raft_stage1_kernel<<<dim3(B_ * (N_ / TN)), dim3(512), 0, stream>>>(f1Tf, f2T, cand);

    raft_zero_kernel<<<dim3(1), dim3(64), 0, stream>>>(gcnt);

    raft_scatter_kernel<<<dim3(256), dim3(256), 0, stream>>>(cand, pairs, gcnt);

    raft_score_kernel<<<dim3(1024), dim3(256), 0, stream>>>(
        f1Tf, f2Tf, cand, pairs, gcnt, cs);

    raft_rank_kernel<<<dim3(1024), dim3(RR * CK2), 0, stream>>>(cand, cs, (float*)d_out);
}

// Round 8
// 311.836 us; speedup vs baseline: 1.3198x; 1.3198x over previous
//
#include <hip/hip_runtime.h>
#include <hip/hip_bf16.h>

// Problem constants (fixed by setup_inputs)
#define B_  2
#define C_  256
#define H_  64
#define W_  128
#define N_  (H_ * W_)   // 8192
#define K_  32          // top-k
#define Q_  10          // per-lane register queue depth (32 queues/row)
#define CK2 36          // candidates per row handed to stage 2 (bf16-sorted)
#define TN  32          // n-rows per block
#define TM  16          // m-rows per wave per m-tile
#define NHT 64          // m-tiles per wave (1024 m / 16)
#define RR  32          // rerank rows per block (32*36 = 1152 = 576 thr x 2)

typedef short  short8  __attribute__((ext_vector_type(8)));
typedef short  short4v __attribute__((ext_vector_type(4)));
typedef float  floatx4 __attribute__((ext_vector_type(4)));

__device__ __forceinline__ unsigned umin_(unsigned a, unsigned b) { return a < b ? a : b; }
__device__ __forceinline__ unsigned umax_(unsigned a, unsigned b) { return a > b ? a : b; }
__device__ __forceinline__ ushort f2bf(float v) {
    __hip_bfloat16 h = __float2bfloat16(v);   // RNE
    ushort u; __builtin_memcpy(&u, &h, 2); return u;
}
// hardware median-of-3 (valid as shift-insert because q[i] <= q[i-1])
__device__ __forceinline__ unsigned med3u(unsigned a, unsigned b, unsigned c) {
    unsigned d;
    asm("v_med3_u32 %0, %1, %2, %3" : "=v"(d) : "v"(a), "v"(b), "v"(c));
    return d;
}

// key: top-19 bits of fp32 (clamped >=0, monotone) | 13-bit m index
__device__ __forceinline__ unsigned packkey(float v, int m) {
    const float vc = v > 0.0f ? v : 0.0f;
    unsigned b; __builtin_memcpy(&b, &vc, 4);
    return (b & 0xFFFFE000u) | (unsigned)m;
}

// descending-sorted register queue insert via v_med3_u32
__device__ __forceinline__ void qinsert(unsigned (&q)[Q_], unsigned k) {
#pragma unroll
    for (int i = Q_ - 1; i > 0; --i)
        q[i] = med3u(q[i - 1], k, q[i]);
    q[0] = umax_(q[0], k);
}

#define CSWAP(a, b) { const unsigned _mx = umax_(a, b); \
                      const unsigned _mn = umin_(a, b); (a) = _mx; (b) = _mn; }

// async global->LDS DMA, 16 B per lane. LDS dest is wave-uniform base +
// lane*16 (HW-added); global src is per-lane.
__device__ __forceinline__ void gl_lds16(const ushort* g, ushort* l) {
    __builtin_amdgcn_global_load_lds(
        (const __attribute__((address_space(1))) unsigned int*)(g),
        (__attribute__((address_space(3))) unsigned int*)(l),
        16, 0, 0);
}

// ---------------------------------------------------------------------------
// Kernel 1: prep (vectorized). fp32 [B][C][N] -> f1Tf fp32 [B][N][C],
//           f2Tf fp32 [B][N][C], f2T bf16 [B][N][C]
// ---------------------------------------------------------------------------
__global__ void raft_prep_kernel(const float* __restrict__ f1,
                                 const float* __restrict__ f2,
                                 float* __restrict__ f1Tf,
                                 ushort* __restrict__ f2T,
                                 float* __restrict__ f2Tf) {
    __shared__ float tile[32][33];
    const int nt = blockIdx.x;
    const int ct = blockIdx.y;
    const int z  = blockIdx.z;          // b*2 + which
    const int b  = z >> 1;
    const float* __restrict__ src = (z & 1) ? f2 : f1;
    const int tid = threadIdx.x;

    {
        const int cl = tid >> 3;        // 0..31
        const int nx = tid & 7;         // 0..7 (x4 n)
        const float4 v = *(const float4*)(
            src + ((size_t)b * C_ + (ct * 32 + cl)) * N_ + (nt * 32 + nx * 4));
        tile[cl][nx * 4 + 0] = v.x;
        tile[cl][nx * 4 + 1] = v.y;
        tile[cl][nx * 4 + 2] = v.z;
        tile[cl][nx * 4 + 3] = v.w;
    }
    __syncthreads();
    {
        const int nl = tid >> 3;        // 0..31
        const int c4 = (tid & 7) * 4;   // 0,4,..28
        float4 v;
        v.x = tile[c4 + 0][nl];
        v.y = tile[c4 + 1][nl];
        v.z = tile[c4 + 2][nl];
        v.w = tile[c4 + 3][nl];
        const size_t o = ((size_t)b * N_ + (nt * 32 + nl)) * C_ + (ct * 32 + c4);
        if (z & 1) {
            *(float4*)(f2Tf + o) = v;
            short4v h;
            h[0] = (short)f2bf(v.x); h[1] = (short)f2bf(v.y);
            h[2] = (short)f2bf(v.z); h[3] = (short)f2bf(v.w);
            *(short4v*)(f2T + o) = h;
        } else {
            *(float4*)(f1Tf + o) = v;
        }
    }
}

// ---------------------------------------------------------------------------
// Kernel 2: stage-1 (ROUND-4 VERBATIM, measured 159 us). 512 thr = 8 waves,
// each wave owns a private m-eighth and holds BOTH n-strips in registers
// (af[2]) -> each ds_read_b128 feeds 2 MFMAs; staged bytes written once (DMA)
// + read once. K split into two 128-col phases with LDS double-buffer; one
// __syncthreads per phase (its vmcnt(0) drain is the DMA completion wait).
// ---------------------------------------------------------------------------
__launch_bounds__(512, 4)
__global__ void raft_stage1_kernel(const float* __restrict__ f1Tf,
                                   const ushort* __restrict__ f2T,
                                   ushort* __restrict__ cand) {
    // [kh][eighth][16 rows x 16 chunks x 8 ushorts] = 2 x 32 KiB
    __shared__ __align__(16) ushort Bt[2][8][2048];

    // XCD-bijective swizzle: 512 = 8 XCDs x 64; each XCD serves one batch.
    const int bid0 = blockIdx.x;
    const int bid  = ((bid0 & 7) << 6) | (bid0 >> 3);
    const int b    = bid >> 8;
    const int nt0  = (bid & 255) * TN;
    const int tid  = threadIdx.x;
    const int w    = tid >> 6;                   // wave 0..7 = m-eighth
    const int lane = tid & 63;
    const int p    = lane & 15;
    const int q4   = lane >> 4;

    // ---- f1 fragments (B-operand), both n-strips: fp32 -> bf16 RNE ----
    short8 af[2][8];
    #pragma unroll
    for (int ns = 0; ns < 2; ++ns) {
        const float* __restrict__ arow =
            f1Tf + ((size_t)b * N_ + nt0 + ns * 16 + p) * C_;
        #pragma unroll
        for (int ks = 0; ks < 8; ++ks) {
            const float4 x = *(const float4*)(arow + ks * 32 + q4 * 8);
            const float4 y = *(const float4*)(arow + ks * 32 + q4 * 8 + 4);
            short8 t;
            t[0] = (short)f2bf(x.x); t[1] = (short)f2bf(x.y);
            t[2] = (short)f2bf(x.z); t[3] = (short)f2bf(x.w);
            t[4] = (short)f2bf(y.x); t[5] = (short)f2bf(y.y);
            t[6] = (short)f2bf(y.z); t[7] = (short)f2bf(y.w);
            af[ns][ks] = t;
        }
    }

    unsigned q0[Q_], q1[Q_];
    #pragma unroll
    for (int i = 0; i < Q_; ++i) { q0[i] = 0u; q1[i] = 0u; }

    // ---- DMA source map: half-tile = 2048 slots of 16 B, slot s holds
    //      global (row r, chunk c = c' ^ (r&7)) of eighth es; linear LDS.
    //      s = w*64 + i*512 + lane  (i = 0..3 instrs per wave)
    const ushort* __restrict__ f2Tb = f2T + (size_t)b * N_ * C_;
    const ushort* gsrc[4];
    #pragma unroll
    for (int i = 0; i < 4; ++i) {
        const int s  = w * 64 + i * 512 + lane;
        const int es = s >> 8;                 // 0..7
        const int r  = (s >> 4) & 15;          // row in sub-tile
        const int cc = (s & 15) ^ (r & 7);     // source chunk (inverse swizzle)
        gsrc[i] = f2Tb + ((size_t)es * 1024 + r) * C_ + cc * 8;
    }
    const int sbase = (w * 64) * 8;            // ushort offset of wave slot base

    // ---- prologue: DMA (mt=0, kh=0) into Bt[0] ----
    #pragma unroll
    for (int i = 0; i < 4; ++i)
        gl_lds16(gsrc[i], &Bt[0][0][0] + sbase + i * 512 * 8);
    __syncthreads();

    floatx4 acc0, acc1;
    for (int mt = 0; mt < NHT; ++mt) {
        // ============ phase kh = 0 : read Bt[0], stage (mt,1) -> Bt[1] ======
        {
            const size_t off = (size_t)mt * TM * C_ + 128;
            #pragma unroll
            for (int i = 0; i < 4; ++i)
                gl_lds16(gsrc[i] + off, &Bt[1][0][0] + sbase + i * 512 * 8);
        }
        acc0 = (floatx4){0.f, 0.f, 0.f, 0.f};
        acc1 = (floatx4){0.f, 0.f, 0.f, 0.f};
        {
            const ushort* __restrict__ cur = &Bt[0][w][0];
            #pragma unroll
            for (int ks = 0; ks < 4; ++ks) {
                const int c = ks * 4 + q4;
                const short8 bm = *(const short8*)(&cur[(p * 16 + (c ^ (p & 7))) * 8]);
                acc0 = __builtin_amdgcn_mfma_f32_16x16x32_bf16(bm, af[0][ks], acc0, 0, 0, 0);
                acc1 = __builtin_amdgcn_mfma_f32_16x16x32_bf16(bm, af[1][ks], acc1, 0, 0, 0);
            }
        }
        __syncthreads();   // Bt[1] DMA landed; everyone done reading Bt[0]

        // ============ phase kh = 1 : read Bt[1], stage (mt+1,0) -> Bt[0] ====
        if (mt + 1 < NHT) {
            const size_t off = (size_t)(mt + 1) * TM * C_;
            #pragma unroll
            for (int i = 0; i < 4; ++i)
                gl_lds16(gsrc[i] + off, &Bt[0][0][0] + sbase + i * 512 * 8);
        }
        {
            const ushort* __restrict__ cur = &Bt[1][w][0];
            #pragma unroll
            for (int ks = 0; ks < 4; ++ks) {
                const int c = ks * 4 + q4;
                const short8 bm = *(const short8*)(&cur[(p * 16 + (c ^ (p & 7))) * 8]);
                acc0 = __builtin_amdgcn_mfma_f32_16x16x32_bf16(bm, af[0][4 + ks], acc0, 0, 0, 0);
                acc1 = __builtin_amdgcn_mfma_f32_16x16x32_bf16(bm, af[1][4 + ks], acc1, 0, 0, 0);
            }
        }

        // ---- in-register filter: same m-class, two n-rows ----
        const int mb = w * 1024 + mt * TM + q4 * 4;
        {
            unsigned k0 = packkey(acc0[0], mb + 0);
            unsigned k1 = packkey(acc0[1], mb + 1);
            unsigned k2 = packkey(acc0[2], mb + 2);
            unsigned k3 = packkey(acc0[3], mb + 3);
            CSWAP(k0, k1); CSWAP(k2, k3); CSWAP(k0, k2); CSWAP(k1, k3); CSWAP(k1, k2);
            qinsert(q0, k0);
            if (__any(k1 > q0[Q_ - 1])) {
                qinsert(q0, k1);
                if (__any(k2 > q0[Q_ - 1])) {
                    qinsert(q0, k2);
                    if (__any(k3 > q0[Q_ - 1])) qinsert(q0, k3);
                }
            }
        }
        {
            unsigned k0 = packkey(acc1[0], mb + 0);
            unsigned k1 = packkey(acc1[1], mb + 1);
            unsigned k2 = packkey(acc1[2], mb + 2);
            unsigned k3 = packkey(acc1[3], mb + 3);
            CSWAP(k0, k1); CSWAP(k2, k3); CSWAP(k0, k2); CSWAP(k1, k3); CSWAP(k1, k2);
            qinsert(q1, k0);
            if (__any(k1 > q1[Q_ - 1])) {
                qinsert(q1, k1);
                if (__any(k2 > q1[Q_ - 1])) {
                    qinsert(q1, k2);
                    if (__any(k3 > q1[Q_ - 1])) qinsert(q1, k3);
                }
            }
        }
        __syncthreads();   // Bt[0] DMA landed; everyone done reading Bt[1]
    }

    // ---- tail: 32 sorted depth-10 lists per row -> bf16-sorted top-36 ----
    unsigned* __restrict__ smem = (unsigned*)&Bt[0][0][0];
    const int qi = w * 4 + q4;
    #pragma unroll
    for (int t = 0; t < Q_; ++t) {
        smem[(qi * Q_ + t) * 33 + p]      = q0[t];
        smem[(qi * Q_ + t) * 33 + 16 + p] = q1[t];
    }
    __syncthreads();

    // stage A: 128 threads: (row r, group g of 8 lists) 8-way merge -> top-36
    unsigned* __restrict__ ms = smem + 10560;    // 32*10*33 span
    if (tid < 128) {
        const int r = tid >> 2, g = tid & 3;
        const int lb = g * 8;
        int i0 = 0, i1 = 0, i2 = 0, i3 = 0, i4 = 0, i5 = 0, i6 = 0, i7 = 0;
        for (int t = 0; t < CK2; ++t) {
            const unsigned a0 = (i0 < Q_) ? smem[((lb + 0) * Q_ + i0) * 33 + r] : 0u;
            const unsigned a1 = (i1 < Q_) ? smem[((lb + 1) * Q_ + i1) * 33 + r] : 0u;
            const unsigned a2 = (i2 < Q_) ? smem[((lb + 2) * Q_ + i2) * 33 + r] : 0u;
            const unsigned a3 = (i3 < Q_) ? smem[((lb + 3) * Q_ + i3) * 33 + r] : 0u;
            const unsigned a4 = (i4 < Q_) ? smem[((lb + 4) * Q_ + i4) * 33 + r] : 0u;
            const unsigned a5 = (i5 < Q_) ? smem[((lb + 5) * Q_ + i5) * 33 + r] : 0u;
            const unsigned a6 = (i6 < Q_) ? smem[((lb + 6) * Q_ + i6) * 33 + r] : 0u;
            const unsigned a7 = (i7 < Q_) ? smem[((lb + 7) * Q_ + i7) * 33 + r] : 0u;
            const unsigned mx = umax_(umax_(umax_(a0, a1), umax_(a2, a3)),
                                      umax_(umax_(a4, a5), umax_(a6, a7)));
            ms[(g * CK2 + t) * 33 + r] = mx;
            const bool e0 = (a0 == mx);
            const bool e1 = !e0 && (a1 == mx);
            const bool e2 = !e0 && !e1 && (a2 == mx);
            const bool e3 = !e0 && !e1 && !e2 && (a3 == mx);
            const bool e4 = !e0 && !e1 && !e2 && !e3 && (a4 == mx);
            const bool e5 = !e0 && !e1 && !e2 && !e3 && !e4 && (a5 == mx);
            const bool e6 = !e0 && !e1 && !e2 && !e3 && !e4 && !e5 && (a6 == mx);
            const bool e7 = !e0 && !e1 && !e2 && !e3 && !e4 && !e5 && !e6 && (a7 == mx);
            i0 += e0; i1 += e1; i2 += e2; i3 += e3;
            i4 += e4; i5 += e5; i6 += e6; i7 += e7;
        }
    }
    __syncthreads();

    // stage B: 32 threads (one per row): 4-way merge, take first 36, emit idx
    if (tid < 32) {
        int i0 = 0, i1 = 0, i2 = 0, i3 = 0;
        ushort* __restrict__ myc = cand + ((size_t)(b * N_ + nt0 + tid)) * CK2;
        for (int t = 0; t < CK2; ++t) {
            const unsigned a0 = ms[(0 * CK2 + i0) * 33 + tid];
            const unsigned a1 = ms[(1 * CK2 + i1) * 33 + tid];
            const unsigned a2 = ms[(2 * CK2 + i2) * 33 + tid];
            const unsigned a3 = ms[(3 * CK2 + i3) * 33 + tid];
            const unsigned m01 = umax_(a0, a1), m23 = umax_(a2, a3);
            const unsigned mx  = umax_(m01, m23);
            myc[t] = (ushort)(mx & 0x1FFFu);
            i0 += (a0 == mx);
            i1 += (a0 != mx) & (a1 == mx);
            i2 += (a0 != mx) & (a1 != mx) & (a2 == mx);
            i3 += (a0 != mx) & (a1 != mx) & (a2 != mx) & (a3 == mx);
        }
    }
}

// ---------------------------------------------------------------------------
// Kernel 3: stage-2 — fused exact-fp32 re-rank + epilogue, ILP-restructured.
// grid: 512 blocks x 576 threads; 32 rows/block; each thread owns TWO pairs
// (tid -> row r, tid+576 -> row r+16, same candidate slot) as two INTERLEAVED
// sequential-FMA chains. Per-pair summation order (single acc, c ascending)
// is unchanged -> scores bit-identical to all previous passing rounds; the
// interleave + unroll gives >=8 independent b-row loads in flight per thread
// (round-7 profile: VALUBusy 2.6%, 36 VGPR -> pure latency-bound, ~1 load
// ahead; this was the rerank bottleneck, not locality).
// ---------------------------------------------------------------------------
__launch_bounds__(576)
__global__ void raft_rerank_kernel(const float* __restrict__ f1Tf,  // [B][N][C]
                                   const float* __restrict__ f2Tf,  // [B][N][C]
                                   const ushort* __restrict__ cand, // [B*N][CK2]
                                   float* __restrict__ out) {
    __shared__ float  aS[RR][C_];
    __shared__ float  cs[RR][CK2];
    __shared__ ushort cmS[RR][CK2];
    const int bid0 = blockIdx.x;                        // 0..511
    const int bid  = ((bid0 & 7) << 6) | (bid0 >> 3);   // XCD-bijective (512%8==0)
    const int row0 = bid * RR;
    const int tid  = threadIdx.x;      // 0..575
    const int bb   = row0 >> 13;       // all 32 rows of a block share a batch

    // load aS: RR rows x 64 float4 = 2048 float4 over 576 threads
    for (int sidx = tid; sidx < RR * (C_ / 4); sidx += 576) {
        const int rr = sidx >> 6, s4 = sidx & 63;
        *(float4*)(&aS[rr][s4 * 4]) =
            *(const float4*)(f1Tf + ((size_t)(row0 + rr)) * C_ + s4 * 4);
    }
    const int rA = tid / CK2;          // 0..15
    const int cA = tid - rA * CK2;     // 0..35
    const int rB = rA + 16;
    cmS[rA][cA] = cand[(size_t)(row0 + rA) * CK2 + cA];
    cmS[rB][cA] = cand[(size_t)(row0 + rB) * CK2 + cA];
    __syncthreads();

    // two interleaved exact dots; per-pair order identical to previous rounds
    {
        const int mA = cmS[rA][cA];
        const int mB = cmS[rB][cA];
        const float* __restrict__ bRa = f2Tf + ((size_t)bb * N_ + mA) * C_;
        const float* __restrict__ bRb = f2Tf + ((size_t)bb * N_ + mB) * C_;
        float accA = 0.0f, accB = 0.0f;
        #pragma unroll 4
        for (int c4 = 0; c4 < C_; c4 += 4) {
            const float4 xA = *(const float4*)(bRa + c4);
            const float4 xB = *(const float4*)(bRb + c4);
            accA = fmaf(aS[rA][c4 + 0], xA.x, accA);
            accA = fmaf(aS[rA][c4 + 1], xA.y, accA);
            accA = fmaf(aS[rA][c4 + 2], xA.z, accA);
            accA = fmaf(aS[rA][c4 + 3], xA.w, accA);
            accB = fmaf(aS[rB][c4 + 0], xB.x, accB);
            accB = fmaf(aS[rB][c4 + 1], xB.y, accB);
            accB = fmaf(aS[rB][c4 + 2], xB.z, accB);
            accB = fmaf(aS[rB][c4 + 3], xB.w, accB);
        }
        cs[rA][cA] = accA;
        cs[rB][cA] = accB;
    }
    __syncthreads();

    #pragma unroll
    for (int pp = 0; pp < 2; ++pp) {
        const int r  = (pp == 0) ? rA : rB;
        const int c  = cA;
        const int rg = row0 + r;
        const int n  = rg & (N_ - 1);
        const int y0 = n >> 7, x0 = n & 127;
        {
            const float v = cs[r][c];
            const int m = cmS[r][c];
            int rank = 0;
            for (int j = 0; j < CK2; ++j) {
                const float vj = cs[r][j];
                rank += (vj > v) || ((vj == v) && (cmS[r][j] < m));
            }
            if (rank < K_) {
                const size_t posn = (size_t)rank * N_ + n;
                out[(size_t)bb * (K_ * N_) + posn] = v * 0.0625f;   // /sqrt(256)
                const size_t c1b = (size_t)1572864 + (size_t)bb * 2 * K_ * N_;
                out[c1b + posn]                     = (float)((m >> 7) - y0);
                out[c1b + (size_t)(K_ * N_) + posn] = (float)((m & 127) - x0);
            }
        }
        if (c < K_) {
            const size_t posn = (size_t)c * N_ + n;
            const size_t c0b = (size_t)524288 + (size_t)bb * 2 * K_ * N_;
            out[c0b + posn]                     = (float)y0;
            out[c0b + (size_t)(K_ * N_) + posn] = (float)x0;
            out[(size_t)2621440 + (size_t)bb * (K_ * N_) + posn] = (float)bb;
        }
    }
}

// ---------------------------------------------------------------------------
extern "C" void kernel_launch(void* const* d_in, const int* in_sizes, int n_in,
                              void* d_out, int out_size, void* d_ws, size_t ws_size,
                              hipStream_t stream) {
    const float* f1 = (const float*)d_in[0];   // [B][C][N] fp32
    const float* f2 = (const float*)d_in[1];

    float*  f1Tf = (float*)d_ws;                             // 16,777,216 B
    float*  f2Tf = f1Tf + (size_t)B_ * N_ * C_;              // 16,777,216 B
    ushort* f2T  = (ushort*)(f2Tf + (size_t)B_ * N_ * C_);   //  8,388,608 B
    ushort* cand = f2T + (size_t)B_ * N_ * C_;               //  1,179,648 B

    raft_prep_kernel<<<dim3(N_ / 32, C_ / 32, B_ * 2), dim3(256), 0, stream>>>(
        f1, f2, f1Tf, f2T, f2Tf);

    raft_stage1_kernel<<<dim3(B_ * (N_ / TN)), dim3(512), 0, stream>>>(f1Tf, f2T, cand);

    raft_rerank_kernel<<<dim3(B_ * N_ / RR), dim3(576), 0, stream>>>(
        f1Tf, f2Tf, cand, (float*)d_out);
}